// Round 1
// baseline (1654.580 us; speedup 1.0000x reference)
//
#include <hip/hip_runtime.h>
#include <math.h>

#define BB 64
#define HH 512
#define VV 50000
#define LL 400
#define MM 128
#define DD 64
#define HC 260
#define EPSF 1e-8f

__device__ __forceinline__ float sigmoidf(float x){ return 1.0f/(1.0f+expf(-x)); }
__device__ __forceinline__ float wave_max(float v){
  #pragma unroll
  for(int o=32;o;o>>=1) v = fmaxf(v, __shfl_xor(v,o));
  return v;
}
__device__ __forceinline__ float wave_sum(float v){
  #pragma unroll
  for(int o=32;o;o>>=1) v += __shfl_xor(v,o);
  return v;
}

// ---------------- embed + concat builders ----------------
__global__ void k_embed(const int* __restrict__ ids, const float* __restrict__ emb,
                        const float* __restrict__ h0, float* __restrict__ xcat1,
                        float* __restrict__ xcat2){
  int idx = blockIdx.x*256 + threadIdx.x;           // 64*512
  if (idx >= BB*HH) return;
  int b = idx >> 9, h = idx & 511;
  float e = emb[(long)ids[b]*HH + h];
  xcat1[b*1024 + h] = e;
  xcat2[b*1024 + h] = e;
  xcat1[b*1024 + 512 + h] = h0[idx];
}

// ---------------- generic GEMM: C(64,N) = A(64,K) @ W(N,K)^T (+bias) ----------------
// ACC: accumulate into C.  NB: number of bias vectors (0,1,2).
template<int ACC, int NB>
__global__ __launch_bounds__(256) void k_gemm(const float* __restrict__ A,
                                              const float* __restrict__ W,
                                              const float* __restrict__ bias1,
                                              const float* __restrict__ bias2,
                                              float* __restrict__ C,
                                              int K, int N, int ldc){
  __shared__ __align__(16) float As[32][68];
  __shared__ __align__(16) float Ws[32][68];
  int tid = threadIdx.x;
  int n0  = blockIdx.x * 64;
  int tn  = (tid & 15) * 4;
  int tb  = (tid >> 4) * 4;
  int kk  = tid & 31;
  int r0  = tid >> 5;        // 0..7
  float acc[4][4] = {};
  for (int k0 = 0; k0 < K; k0 += 32){
    int kg = k0 + kk;
    bool kv = kg < K;
    #pragma unroll
    for (int i = 0; i < 8; i++){
      int b = r0 + i*8;
      As[kk][b] = kv ? A[(long)b*K + kg] : 0.0f;
      int n = n0 + r0 + i*8;
      Ws[kk][r0 + i*8] = (kv && n < N) ? W[(long)n*K + kg] : 0.0f;
    }
    __syncthreads();
    #pragma unroll
    for (int k = 0; k < 32; k++){
      float4 a4 = *(const float4*)&As[k][tb];
      float4 w4 = *(const float4*)&Ws[k][tn];
      acc[0][0] += a4.x*w4.x; acc[0][1] += a4.x*w4.y; acc[0][2] += a4.x*w4.z; acc[0][3] += a4.x*w4.w;
      acc[1][0] += a4.y*w4.x; acc[1][1] += a4.y*w4.y; acc[1][2] += a4.y*w4.z; acc[1][3] += a4.y*w4.w;
      acc[2][0] += a4.z*w4.x; acc[2][1] += a4.z*w4.y; acc[2][2] += a4.z*w4.z; acc[2][3] += a4.z*w4.w;
      acc[3][0] += a4.w*w4.x; acc[3][1] += a4.w*w4.y; acc[3][2] += a4.w*w4.z; acc[3][3] += a4.w*w4.w;
    }
    __syncthreads();
  }
  #pragma unroll
  for (int i = 0; i < 4; i++){
    int b = tb + i;
    #pragma unroll
    for (int j = 0; j < 4; j++){
      int n = n0 + tn + j;
      if (n < N){
        float v = acc[i][j];
        if (NB >= 1) v += bias1[n];
        if (NB >= 2) v += bias2[n];
        float* p = &C[(long)b*ldc + n];
        if (ACC) *p += v; else *p = v;
      }
    }
  }
}

// ---------------- new_coverage = coverage + ia ----------------
__global__ void k_cov(const float* __restrict__ cov, const float* __restrict__ ia,
                      float* __restrict__ out){
  int idx = blockIdx.x*256 + threadIdx.x;     // 25600
  if (idx >= BB*LL) return;
  out[idx] = cov[idx] + ia[idx];
}

// ---------------- aw = softmax(tc+ia+ts) over L ----------------
__global__ __launch_bounds__(256) void k_softmax_aw(const float* __restrict__ ia,
                                                    const float* __restrict__ ts,
                                                    const float* __restrict__ tc,
                                                    float* __restrict__ aw){
  int b = blockIdx.x, t = threadIdx.x;
  int i0 = t, i1 = t + 256;
  float x0 = ia[b*LL+i0] + ts[b*LL+i0] + tc[b*LL+i0];
  float x1 = (i1 < LL) ? (ia[b*LL+i1] + ts[b*LL+i1] + tc[b*LL+i1]) : -INFINITY;
  __shared__ float sm[4], ss[4];
  float m = wave_max(fmaxf(x0, x1));
  if ((t & 63) == 0) sm[t>>6] = m;
  __syncthreads();
  m = fmaxf(fmaxf(sm[0], sm[1]), fmaxf(sm[2], sm[3]));
  float e0 = expf(x0 - m);
  float e1 = (i1 < LL) ? expf(x1 - m) : 0.0f;
  float s = wave_sum(e0 + e1);
  if ((t & 63) == 0) ss[t>>6] = s;
  __syncthreads();
  float tot = ss[0] + ss[1] + ss[2] + ss[3];
  float inv = 1.0f / tot;
  aw[b*LL + i0] = e0 * inv;
  if (i1 < LL) aw[b*LL + i1] = e1 * inv;
}

// ---------------- attn_applied partials: grid (64 b, 8 l-chunks) ----------------
__global__ __launch_bounds__(256) void k_attn_part(const float* __restrict__ aw,
                                                   const float* __restrict__ enc,
                                                   float* __restrict__ part){
  int b = blockIdx.x, lc = blockIdx.y, t = threadIdx.x;
  const float* awb = aw + b*LL + lc*50;
  const float* eb  = enc + ((long)b*LL + lc*50)*HH;
  float a0 = 0.f, a1 = 0.f;
  for (int l = 0; l < 50; l++){
    float a = awb[l];
    a0 += a * eb[(long)l*HH + t];
    a1 += a * eb[(long)l*HH + t + 256];
  }
  part[((b*8 + lc) << 9) + t]       = a0;
  part[((b*8 + lc) << 9) + t + 256] = a1;
}

__global__ void k_attn_reduce(const float* __restrict__ part, float* __restrict__ xcat2){
  int idx = blockIdx.x*256 + threadIdx.x;       // 64*512
  if (idx >= BB*HH) return;
  int b = idx >> 9, h = idx & 511;
  float s = 0.f;
  #pragma unroll
  for (int lc = 0; lc < 8; lc++) s += part[((b*8 + lc) << 9) + h];
  xcat2[b*1024 + 512 + h] = s;
}

// ---------------- pre GEMMs (K = 8704 split into 17 chunks of 512) ----------------
__global__ __launch_bounds__(256) void k_pre_partial(const float* __restrict__ h0,
                                                     const float* __restrict__ mem,
                                                     const float* __restrict__ rW,
                                                     const float* __restrict__ wW,
                                                     float* __restrict__ part){
  int c = blockIdx.x;          // 0..16
  int which = blockIdx.y;      // 0=r, 1=w
  const float* W = which ? wW : rW;     // (64, 8704)
  __shared__ __align__(16) float As[32][68];
  __shared__ __align__(16) float Ws[32][68];
  int tid = threadIdx.x;
  int kk = tid & 31, r0 = tid >> 5;
  int tn = (tid & 15)*4, tb = (tid >> 4)*4;
  float acc[4][4] = {};
  for (int s = 0; s < 16; s++){
    int kg = c*512 + s*32 + kk;
    #pragma unroll
    for (int i = 0; i < 8; i++){
      int b = r0 + i*8;
      As[kk][b] = (c == 0) ? h0[b*HH + kg] : mem[(long)b*8192 + (kg - 512)];
      Ws[kk][r0 + i*8] = W[(long)(r0 + i*8)*8704 + kg];
    }
    __syncthreads();
    #pragma unroll
    for (int k = 0; k < 32; k++){
      float4 a4 = *(const float4*)&As[k][tb];
      float4 w4 = *(const float4*)&Ws[k][tn];
      acc[0][0] += a4.x*w4.x; acc[0][1] += a4.x*w4.y; acc[0][2] += a4.x*w4.z; acc[0][3] += a4.x*w4.w;
      acc[1][0] += a4.y*w4.x; acc[1][1] += a4.y*w4.y; acc[1][2] += a4.y*w4.z; acc[1][3] += a4.y*w4.w;
      acc[2][0] += a4.z*w4.x; acc[2][1] += a4.z*w4.y; acc[2][2] += a4.z*w4.z; acc[2][3] += a4.z*w4.w;
      acc[3][0] += a4.w*w4.x; acc[3][1] += a4.w*w4.y; acc[3][2] += a4.w*w4.z; acc[3][3] += a4.w*w4.w;
    }
    __syncthreads();
  }
  float* p = part + (which*17 + c)*4096;
  #pragma unroll
  for (int i = 0; i < 4; i++)
    #pragma unroll
    for (int j = 0; j < 4; j++)
      p[(tb + i)*64 + tn + j] = acc[i][j];
}

__global__ void k_pre_reduce(const float* __restrict__ part, const float* __restrict__ rb,
                             const float* __restrict__ wb, float* __restrict__ pre_r,
                             float* __restrict__ pre_w){
  int idx = blockIdx.x*256 + threadIdx.x;     // 8192
  if (idx >= 8192) return;
  int which = idx >> 12;
  int bj = idx & 4095;
  const float* p = part + which*17*4096 + bj;
  float s = 0.f;
  #pragma unroll
  for (int c = 0; c < 17; c++) s += p[c*4096];
  int j = bj & 63;
  s += which ? wb[j] : rb[j];
  (which ? pre_w : pre_r)[bj] = s;
}

// ---------------- LSTM elementwise ----------------
__global__ void k_lstm(const float* __restrict__ g, const float* __restrict__ cprev,
                       float* __restrict__ hout, float* __restrict__ cout,
                       int HCx, int n){
  int idx = blockIdx.x*256 + threadIdx.x;
  if (idx >= n) return;
  int b = idx / HCx, j = idx - b*HCx;
  const float* gb = g + (long)b*4*HCx;
  float gi = gb[j], gf = gb[HCx + j], gg = gb[2*HCx + j], go = gb[3*HCx + j];
  float c2 = sigmoidf(gf)*cprev[idx] + sigmoidf(gi)*tanhf(gg);
  float h  = sigmoidf(go)*tanhf(c2);
  hout[idx] = h;
  if (cout) cout[idx] = c2;
}

// ---------------- addressing: one block per b, 128 threads (m) ----------------
__global__ __launch_bounds__(128) void k_address(const float* __restrict__ hc,
                                                 const float* __restrict__ heads0,
                                                 const float* __restrict__ mem,
                                                 float* __restrict__ wout){
  int b = blockIdx.x, m = threadIdx.x;
  const float* mr = mem + ((long)b*MM + m)*DD;
  float s = 0.f, q = 0.f;
  #pragma unroll 8
  for (int d = 0; d < DD; d++){ float v = mr[d]; s += v; q += v*v; }
  float key  = hc[b*HC + m];
  float kstr = expf(hc[b*HC + 64]);
  float gate = sigmoidf(hc[b*HC + 65]);
  float nk = fmaxf(fabsf(key)*8.0f, EPSF);
  float nm = fmaxf(sqrtf(q), EPSF);
  float z  = kstr * (key*s) / (nk*nm);
  __shared__ float sm[2], ss[2];
  float mx = wave_max(z);
  if ((m & 63) == 0) sm[m>>6] = mx;
  __syncthreads();
  mx = fmaxf(sm[0], sm[1]);
  float e = expf(z - mx);
  float w = wave_sum(e);
  if ((m & 63) == 0) ss[m>>6] = w;
  __syncthreads();
  float content = e / (ss[0] + ss[1]);
  wout[b*MM + m] = gate*content + (1.0f - gate)*heads0[m];   // heads[0]: batch-0 row broadcast (reference semantics)
}

// ---------------- read_in -> xcat3[:,512:576] ----------------
__global__ void k_readin(const float* __restrict__ rw, const float* __restrict__ mem,
                         float* __restrict__ xcat3){
  int b = blockIdx.x, d = threadIdx.x;    // 64 threads
  float s = 0.f;
  for (int m = 0; m < MM; m++) s += rw[b*MM + m] * mem[((long)b*MM + m)*DD + d];
  xcat3[b*576 + 512 + d] = s;
}

// ---------------- new_memory ----------------
__global__ void k_newmem(const float* __restrict__ mem, const float* __restrict__ ww,
                         const float* __restrict__ wh, float* __restrict__ out){
  int idx = blockIdx.x*256 + threadIdx.x;    // 524288
  if (idx >= BB*MM*DD) return;
  int b = idx >> 13;
  int m = (idx & 8191) >> 6;
  float w0 = ww[b*MM + m];
  float we = sigmoidf(wh[b*HC + 68 + m]);
  float wa = sigmoidf(wh[b*HC + 132 + m]);
  out[idx] = mem[idx]*(1.0f - w0*we) + w0*wa;
}

// ---------------- in-place log_softmax over V per b ----------------
__global__ __launch_bounds__(512) void k_logsoftmax(float* __restrict__ lp){
  int b = blockIdx.x, t = threadIdx.x;
  float* row = lp + (long)b*VV;
  float mx = -INFINITY;
  for (int i = t; i < VV; i += 512) mx = fmaxf(mx, row[i]);
  __shared__ float sm[8], ss[8];
  mx = wave_max(mx);
  if ((t & 63) == 0) sm[t>>6] = mx;
  __syncthreads();
  float m2 = -INFINITY;
  #pragma unroll
  for (int i = 0; i < 8; i++) m2 = fmaxf(m2, sm[i]);
  float s = 0.f;
  for (int i = t; i < VV; i += 512) s += expf(row[i] - m2);
  s = wave_sum(s);
  if ((t & 63) == 0) ss[t>>6] = s;
  __syncthreads();
  float tot = 0.f;
  #pragma unroll
  for (int i = 0; i < 8; i++) tot += ss[i];
  float lse = m2 + logf(tot);
  for (int i = t; i < VV; i += 512) row[i] = row[i] - lse;
}

extern "C" void kernel_launch(void* const* d_in, const int* in_sizes, int n_in,
                              void* d_out, int out_size, void* d_ws, size_t ws_size,
                              hipStream_t stream) {
  const int*   ids     = (const int*)  d_in[0];
  const float* h0      = (const float*)d_in[1];
  const float* c0      = (const float*)d_in[2];
  const float* enc     = (const float*)d_in[3];
  // d_in[4] word_occurrence_indicator: unused by reference
  const float* cov     = (const float*)d_in[5];
  const float* mem     = (const float*)d_in[6];
  const float* rheads  = (const float*)d_in[7];
  const float* wheads  = (const float*)d_in[8];
  const float* read_h  = (const float*)d_in[9];
  const float* read_c  = (const float*)d_in[10];
  const float* write_h = (const float*)d_in[11];
  const float* write_c = (const float*)d_in[12];
  const float* emb     = (const float*)d_in[13];
  const float* attn_W  = (const float*)d_in[14];
  const float* attn_b  = (const float*)d_in[15];
  const float* cov_W   = (const float*)d_in[16];
  const float* state_W = (const float*)d_in[17];
  const float* comb_W  = (const float*)d_in[18];
  const float* comb_b  = (const float*)d_in[19];
  const float* rpre_W  = (const float*)d_in[20];
  const float* rpre_b  = (const float*)d_in[21];
  const float* wpre_W  = (const float*)d_in[22];
  const float* wpre_b  = (const float*)d_in[23];
  const float* r_Wih   = (const float*)d_in[24];
  const float* r_Whh   = (const float*)d_in[25];
  const float* r_bih   = (const float*)d_in[26];
  const float* r_bhh   = (const float*)d_in[27];
  const float* w_Wih   = (const float*)d_in[28];
  const float* w_Whh   = (const float*)d_in[29];
  const float* w_bih   = (const float*)d_in[30];
  const float* w_bhh   = (const float*)d_in[31];
  const float* l_Wih   = (const float*)d_in[32];
  const float* l_Whh   = (const float*)d_in[33];
  const float* l_bih   = (const float*)d_in[34];
  const float* l_bhh   = (const float*)d_in[35];
  const float* out_W   = (const float*)d_in[36];
  const float* out_b   = (const float*)d_in[37];

  float* out  = (float*)d_out;
  float* lp   = out;                 // (64, 50000)
  float* h1   = out + 3200000;       // (64, 512)
  float* c1   = h1 + 32768;          // (64, 512)
  float* nmem = c1 + 32768;          // (64, 128, 64)
  float* ncov = nmem + 524288;       // (64, 400)

  float* w = (float*)d_ws;
  float* xcat1 = w;                  // 65536   [embedded | h0]
  float* xcat2 = xcat1 + 65536;      // 65536   [embedded | attn_applied]
  float* xcat3 = xcat2 + 65536;      // 36864   [out0 | read_in]
  float* ia    = xcat3 + 36864;      // 25600
  float* ts    = ia + 25600;         // 25600
  float* tc    = ts + 25600;         // 25600
  float* aw    = tc + 25600;         // 25600
  float* apart = aw + 25600;         // 262144
  float* ppart = apart + 262144;     // 139264
  float* pre_r = ppart + 139264;     // 4096
  float* pre_w = pre_r + 4096;       // 4096
  float* g_r   = pre_w + 4096;       // 66560
  float* g_w   = g_r + 66560;        // 66560
  float* rh    = g_w + 66560;        // 16640
  float* wh    = rh + 16640;         // 16640
  float* rw    = wh + 16640;         // 8192
  float* wwgt  = rw + 8192;          // 8192
  float* g_l   = wwgt + 8192;        // 131072

  // attention path
  k_embed<<<128, 256, 0, stream>>>(ids, emb, h0, xcat1, xcat2);
  k_gemm<0,1><<<7, 256, 0, stream>>>(xcat1, attn_W, attn_b, nullptr, ia, 1024, LL, LL);
  k_cov<<<100, 256, 0, stream>>>(cov, ia, ncov);
  k_gemm<0,0><<<7, 256, 0, stream>>>(c0, state_W, nullptr, nullptr, ts, HH, LL, LL);
  k_gemm<0,0><<<7, 256, 0, stream>>>(ncov, cov_W, nullptr, nullptr, tc, LL, LL, LL);
  k_softmax_aw<<<64, 256, 0, stream>>>(ia, ts, tc, aw);
  k_attn_part<<<dim3(64, 8), 256, 0, stream>>>(aw, enc, apart);
  k_attn_reduce<<<128, 256, 0, stream>>>(apart, xcat2);
  k_gemm<0,1><<<8, 256, 0, stream>>>(xcat2, comb_W, comb_b, nullptr, xcat3, 1024, HH, 576);

  // pre-projections (K=8704 split)
  k_pre_partial<<<dim3(17, 2), 256, 0, stream>>>(h0, mem, rpre_W, wpre_W, ppart);
  k_pre_reduce<<<32, 256, 0, stream>>>(ppart, rpre_b, wpre_b, pre_r, pre_w);

  // read / write head LSTMs
  k_gemm<0,2><<<17, 256, 0, stream>>>(pre_r, r_Wih, r_bih, r_bhh, g_r, 64, 4*HC, 4*HC);
  k_gemm<1,0><<<17, 256, 0, stream>>>(read_h, r_Whh, nullptr, nullptr, g_r, HC, 4*HC, 4*HC);
  k_lstm<<<65, 256, 0, stream>>>(g_r, read_c, rh, nullptr, HC, BB*HC);
  k_gemm<0,2><<<17, 256, 0, stream>>>(pre_w, w_Wih, w_bih, w_bhh, g_w, 64, 4*HC, 4*HC);
  k_gemm<1,0><<<17, 256, 0, stream>>>(write_h, w_Whh, nullptr, nullptr, g_w, HC, 4*HC, 4*HC);
  k_lstm<<<65, 256, 0, stream>>>(g_w, write_c, wh, nullptr, HC, BB*HC);

  // addressing + memory ops
  k_address<<<64, 128, 0, stream>>>(rh, rheads, mem, rw);
  k_address<<<64, 128, 0, stream>>>(wh, wheads, mem, wwgt);
  k_readin<<<64, 64, 0, stream>>>(rw, mem, xcat3);
  k_newmem<<<2048, 256, 0, stream>>>(mem, wwgt, wh, nmem);

  // main LSTM
  k_gemm<0,2><<<32, 256, 0, stream>>>(xcat3, l_Wih, l_bih, l_bhh, g_l, 576, 4*HH, 4*HH);
  k_gemm<1,0><<<32, 256, 0, stream>>>(h0, l_Whh, nullptr, nullptr, g_l, HH, 4*HH, 4*HH);
  k_lstm<<<128, 256, 0, stream>>>(g_l, c0, h1, c1, HH, BB*HH);

  // output projection + log_softmax (in place in d_out)
  k_gemm<0,1><<<782, 256, 0, stream>>>(c1, out_W, out_b, nullptr, lp, HH, VV, VV);
  k_logsoftmax<<<64, 512, 0, stream>>>(lp);
}

// Round 2
// 559.920 us; speedup vs baseline: 2.9550x; 2.9550x over previous
//
#include <hip/hip_runtime.h>
#include <math.h>

#define BB 64
#define HH 512
#define VV 50000
#define LL 400
#define MM 128
#define DD 64
#define HC 260
#define EPSF 1e-8f

__device__ __forceinline__ float sigmoidf(float x){ return 1.0f/(1.0f+expf(-x)); }
__device__ __forceinline__ float wave_max(float v){
  #pragma unroll
  for(int o=32;o;o>>=1) v = fmaxf(v, __shfl_xor(v,o));
  return v;
}
__device__ __forceinline__ float wave_sum(float v){
  #pragma unroll
  for(int o=32;o;o>>=1) v += __shfl_xor(v,o);
  return v;
}

// ---------------- embed + concat builders ----------------
__global__ void k_embed(const int* __restrict__ ids, const float* __restrict__ emb,
                        const float* __restrict__ h0, float* __restrict__ xcat1,
                        float* __restrict__ xcat2){
  int idx = blockIdx.x*256 + threadIdx.x;           // 64*512
  if (idx >= BB*HH) return;
  int b = idx >> 9, h = idx & 511;
  float e = emb[(long)ids[b]*HH + h];
  xcat1[b*1024 + h] = e;
  xcat2[b*1024 + h] = e;
  xcat1[b*1024 + 512 + h] = h0[idx];
}

// ---------------- wave-per-output GEMV: C[b,n] = (A[+A2])[b,:] . W[n,:] ----------------
// grid (ceil(N/4), B); wave w of block computes n = bx*4+w. lda == K required.
template<int NB, int FUSE>
__global__ __launch_bounds__(256) void k_gemv(const float* __restrict__ A,
                                              const float* __restrict__ A2,
                                              const float* __restrict__ W,
                                              const float* __restrict__ b1,
                                              float* __restrict__ C,
                                              int K, int N, int ldc){
  int b = blockIdx.y;
  int wid = threadIdx.x >> 6, lane = threadIdx.x & 63;
  int n = blockIdx.x*4 + wid;
  if (n >= N) return;
  const float4* A4  = (const float4*)(A + (long)b*K);
  const float4* A24 = (const float4*)(A2 + (long)b*K);
  const float4* W4  = (const float4*)(W + (long)n*K);
  int K4 = K >> 2;
  float acc = 0.f;
  for (int k = lane; k < K4; k += 64){
    float4 a = A4[k];
    if (FUSE){ float4 a2 = A24[k]; a.x+=a2.x; a.y+=a2.y; a.z+=a2.z; a.w+=a2.w; }
    float4 w = W4[k];
    acc += a.x*w.x + a.y*w.y + a.z*w.z + a.w*w.w;
  }
  acc = wave_sum(acc);
  if (lane == 0){
    if (NB) acc += b1[n];
    C[(long)b*ldc + n] = acc;
  }
}

// ---------------- new_coverage = coverage + ia ----------------
__global__ void k_cov(const float* __restrict__ cov, const float* __restrict__ ia,
                      float* __restrict__ out){
  int idx = blockIdx.x*256 + threadIdx.x;     // 25600
  if (idx >= BB*LL) return;
  out[idx] = cov[idx] + ia[idx];
}

// ---------------- aw = softmax(tc+ia+ts) over L ----------------
__global__ __launch_bounds__(256) void k_softmax_aw(const float* __restrict__ ia,
                                                    const float* __restrict__ ts,
                                                    const float* __restrict__ tc,
                                                    float* __restrict__ aw){
  int b = blockIdx.x, t = threadIdx.x;
  int i0 = t, i1 = t + 256;
  float x0 = ia[b*LL+i0] + ts[b*LL+i0] + tc[b*LL+i0];
  float x1 = (i1 < LL) ? (ia[b*LL+i1] + ts[b*LL+i1] + tc[b*LL+i1]) : -INFINITY;
  __shared__ float sm[4], ss[4];
  float m = wave_max(fmaxf(x0, x1));
  if ((t & 63) == 0) sm[t>>6] = m;
  __syncthreads();
  m = fmaxf(fmaxf(sm[0], sm[1]), fmaxf(sm[2], sm[3]));
  float e0 = expf(x0 - m);
  float e1 = (i1 < LL) ? expf(x1 - m) : 0.0f;
  float s = wave_sum(e0 + e1);
  if ((t & 63) == 0) ss[t>>6] = s;
  __syncthreads();
  float tot = ss[0] + ss[1] + ss[2] + ss[3];
  float inv = 1.0f / tot;
  aw[b*LL + i0] = e0 * inv;
  if (i1 < LL) aw[b*LL + i1] = e1 * inv;
}

// ---------------- attn_applied partials: grid (64 b, 16 l-chunks of 25) ----------------
__global__ __launch_bounds__(256) void k_attn_part(const float* __restrict__ aw,
                                                   const float* __restrict__ enc,
                                                   float* __restrict__ part){
  int b = blockIdx.x, lc = blockIdx.y, t = threadIdx.x;
  const float* awb = aw + b*LL + lc*25;
  const float* eb  = enc + ((long)b*LL + lc*25)*HH;
  float a0 = 0.f, a1 = 0.f;
  for (int l = 0; l < 25; l++){
    float a = awb[l];
    a0 += a * eb[(long)l*HH + t];
    a1 += a * eb[(long)l*HH + t + 256];
  }
  part[((b*16 + lc) << 9) + t]       = a0;
  part[((b*16 + lc) << 9) + t + 256] = a1;
}

__global__ void k_attn_reduce(const float* __restrict__ part, float* __restrict__ xcat2){
  int idx = blockIdx.x*256 + threadIdx.x;       // 64*512
  if (idx >= BB*HH) return;
  int b = idx >> 9, h = idx & 511;
  float s = 0.f;
  #pragma unroll
  for (int lc = 0; lc < 16; lc++) s += part[((b*16 + lc) << 9) + h];
  xcat2[b*1024 + 512 + h] = s;
}

// ---------------- pre GEMMs: K=8704 in 68 chunks of 128, grid (68, 2) ----------------
__global__ __launch_bounds__(256) void k_pre_partial(const float* __restrict__ h0,
                                                     const float* __restrict__ mem,
                                                     const float* __restrict__ rW,
                                                     const float* __restrict__ wW,
                                                     float* __restrict__ part){
  int c = blockIdx.x;          // 0..67
  int which = blockIdx.y;      // 0=r, 1=w
  const float* W = which ? wW : rW;     // (64, 8704)
  __shared__ __align__(16) float As[32][68];
  __shared__ __align__(16) float Ws[32][68];
  int tid = threadIdx.x;
  int kk = tid & 31, r0 = tid >> 5;
  int tn = (tid & 15)*4, tb = (tid >> 4)*4;
  float acc[4][4] = {};
  for (int s = 0; s < 4; s++){
    int kg = c*128 + s*32 + kk;
    #pragma unroll
    for (int i = 0; i < 8; i++){
      int b = r0 + i*8;
      As[kk][b] = (kg < 512) ? h0[b*HH + kg] : mem[(long)b*8192 + (kg - 512)];
      Ws[kk][r0 + i*8] = W[(long)(r0 + i*8)*8704 + kg];
    }
    __syncthreads();
    #pragma unroll
    for (int k = 0; k < 32; k++){
      float4 a4 = *(const float4*)&As[k][tb];
      float4 w4 = *(const float4*)&Ws[k][tn];
      acc[0][0] += a4.x*w4.x; acc[0][1] += a4.x*w4.y; acc[0][2] += a4.x*w4.z; acc[0][3] += a4.x*w4.w;
      acc[1][0] += a4.y*w4.x; acc[1][1] += a4.y*w4.y; acc[1][2] += a4.y*w4.z; acc[1][3] += a4.y*w4.w;
      acc[2][0] += a4.z*w4.x; acc[2][1] += a4.z*w4.y; acc[2][2] += a4.z*w4.z; acc[2][3] += a4.z*w4.w;
      acc[3][0] += a4.w*w4.x; acc[3][1] += a4.w*w4.y; acc[3][2] += a4.w*w4.z; acc[3][3] += a4.w*w4.w;
    }
    __syncthreads();
  }
  float* p = part + ((long)which*68 + c)*4096;
  #pragma unroll
  for (int i = 0; i < 4; i++)
    #pragma unroll
    for (int j = 0; j < 4; j++)
      p[(tb + i)*64 + tn + j] = acc[i][j];
}

__global__ void k_pre_reduce(const float* __restrict__ part, const float* __restrict__ rb,
                             const float* __restrict__ wb, float* __restrict__ pre_r,
                             float* __restrict__ pre_w){
  int idx = blockIdx.x*256 + threadIdx.x;     // 8192
  if (idx >= 8192) return;
  int which = idx >> 12;
  int bj = idx & 4095;
  const float* p = part + (long)which*68*4096 + bj;
  float s = 0.f;
  #pragma unroll
  for (int c = 0; c < 68; c++) s += p[c*4096];
  int j = bj & 63;
  s += which ? wb[j] : rb[j];
  (which ? pre_w : pre_r)[bj] = s;
}

// ---------------- fused gates GEMV for r/w heads: grid (260, 64, 2) ----------------
__global__ __launch_bounds__(256) void k_gates_rw(const float* __restrict__ pre_r,
    const float* __restrict__ pre_w, const float* __restrict__ read_h,
    const float* __restrict__ write_h,
    const float* __restrict__ rWih, const float* __restrict__ rWhh,
    const float* __restrict__ rbih, const float* __restrict__ rbhh,
    const float* __restrict__ wWih, const float* __restrict__ wWhh,
    const float* __restrict__ wbih, const float* __restrict__ wbhh,
    float* __restrict__ g_r, float* __restrict__ g_w){
  int which = blockIdx.z;
  int b = blockIdx.y;
  int wid = threadIdx.x >> 6, lane = threadIdx.x & 63;
  int n = blockIdx.x*4 + wid;     // < 1040
  const float* pre = which ? pre_w : pre_r;     // (64,64)
  const float* hh  = which ? write_h : read_h;  // (64,260)
  const float* Wih = which ? wWih : rWih;       // (1040,64)
  const float* Whh = which ? wWhh : rWhh;       // (1040,260)
  float acc = pre[b*64 + lane] * Wih[n*64 + lane];
  const float* hb = hh + b*HC;
  const float* wr = Whh + (long)n*HC;
  #pragma unroll
  for (int i = 0; i < 5; i++){
    int k = lane + i*64;
    if (k < HC) acc += hb[k]*wr[k];
  }
  acc = wave_sum(acc);
  if (lane == 0){
    acc += (which ? wbih : rbih)[n] + (which ? wbhh : rbhh)[n];
    (which ? g_w : g_r)[(long)b*4*HC + n] = acc;
  }
}

// ---------------- fused r+w LSTM elementwise ----------------
__global__ void k_lstm_rw(const float* __restrict__ g_r, const float* __restrict__ g_w,
                          const float* __restrict__ read_c, const float* __restrict__ write_c,
                          float* __restrict__ rh, float* __restrict__ wh){
  int idx = blockIdx.x*256 + threadIdx.x;    // 2*64*260 = 33280
  if (idx >= 2*BB*HC) return;
  int which = idx >= BB*HC;
  int r = which ? idx - BB*HC : idx;
  int b = r / HC, j = r - b*HC;
  const float* g = (which ? g_w : g_r) + (long)b*4*HC;
  float c2 = sigmoidf(g[HC + j]) * (which ? write_c : read_c)[r]
           + sigmoidf(g[j]) * tanhf(g[2*HC + j]);
  (which ? wh : rh)[r] = sigmoidf(g[3*HC + j]) * tanhf(c2);
}

// ---------------- addressing: grid (64, 2), 128 threads ----------------
__global__ __launch_bounds__(128) void k_address(const float* __restrict__ rh,
                                                 const float* __restrict__ whv,
                                                 const float* __restrict__ rheads,
                                                 const float* __restrict__ wheads,
                                                 const float* __restrict__ mem,
                                                 float* __restrict__ rwout,
                                                 float* __restrict__ wwout){
  int which = blockIdx.y;
  int b = blockIdx.x, m = threadIdx.x;
  const float* hc = which ? whv : rh;
  const float* heads0 = which ? wheads : rheads;
  float* wout = which ? wwout : rwout;
  const float* mr = mem + ((long)b*MM + m)*DD;
  float s = 0.f, q = 0.f;
  #pragma unroll 8
  for (int d = 0; d < DD; d++){ float v = mr[d]; s += v; q += v*v; }
  float key  = hc[b*HC + m];
  float kstr = expf(hc[b*HC + 64]);
  float gate = sigmoidf(hc[b*HC + 65]);
  float nk = fmaxf(fabsf(key)*8.0f, EPSF);
  float nm = fmaxf(sqrtf(q), EPSF);
  float z  = kstr * (key*s) / (nk*nm);
  __shared__ float sm[2], ss[2];
  float mx = wave_max(z);
  if ((m & 63) == 0) sm[m>>6] = mx;
  __syncthreads();
  mx = fmaxf(sm[0], sm[1]);
  float e = expf(z - mx);
  float w = wave_sum(e);
  if ((m & 63) == 0) ss[m>>6] = w;
  __syncthreads();
  float content = e / (ss[0] + ss[1]);
  wout[b*MM + m] = gate*content + (1.0f - gate)*heads0[m];   // heads[0]: batch-0 row broadcast
}

// ---------------- read_in -> xcat3[:,512:576] ----------------
__global__ void k_readin(const float* __restrict__ rw, const float* __restrict__ mem,
                         float* __restrict__ xcat3){
  int b = blockIdx.x, d = threadIdx.x;    // 64 threads
  float s = 0.f;
  for (int m = 0; m < MM; m++) s += rw[b*MM + m] * mem[((long)b*MM + m)*DD + d];
  xcat3[b*576 + 512 + d] = s;
}

// ---------------- new_memory ----------------
__global__ void k_newmem(const float* __restrict__ mem, const float* __restrict__ ww,
                         const float* __restrict__ wh, float* __restrict__ out){
  int idx = blockIdx.x*256 + threadIdx.x;    // 524288
  if (idx >= BB*MM*DD) return;
  int b = idx >> 13;
  int m = (idx & 8191) >> 6;
  float w0 = ww[b*MM + m];
  float we = sigmoidf(wh[b*HC + 68 + m]);
  float wa = sigmoidf(wh[b*HC + 132 + m]);
  out[idx] = mem[idx]*(1.0f - w0*we) + w0*wa;
}

// ---------------- main-LSTM gates partials: grid (32 n-tiles, 4 k-splits) ----------------
// s=0,1: xcat3 @ l_Wih^T (K=576, halves of 288); s=2,3: h0 @ l_Whh^T (K=512, halves of 256)
__global__ __launch_bounds__(256) void k_lgates_part(const float* __restrict__ xcat3,
                                                     const float* __restrict__ h0,
                                                     const float* __restrict__ lWih,
                                                     const float* __restrict__ lWhh,
                                                     float* __restrict__ part){
  int s = blockIdx.y;
  int n0 = blockIdx.x*64;
  const float *A, *W; int lda, k0, nchunk;
  if (s < 2){ A = xcat3; W = lWih; lda = 576; k0 = s*288; nchunk = 9; }
  else      { A = h0;    W = lWhh; lda = 512; k0 = (s-2)*256; nchunk = 8; }
  __shared__ __align__(16) float As[32][68];
  __shared__ __align__(16) float Ws[32][68];
  int tid = threadIdx.x;
  int kk = tid & 31, r0 = tid >> 5;
  int tn = (tid & 15)*4, tb = (tid >> 4)*4;
  float acc[4][4] = {};
  for (int sc = 0; sc < nchunk; sc++){
    int kg = k0 + sc*32 + kk;
    #pragma unroll
    for (int i = 0; i < 8; i++){
      int r = r0 + i*8;
      As[kk][r] = A[(long)r*lda + kg];
      Ws[kk][r] = W[(long)(n0 + r)*lda + kg];
    }
    __syncthreads();
    #pragma unroll
    for (int k = 0; k < 32; k++){
      float4 a4 = *(const float4*)&As[k][tb];
      float4 w4 = *(const float4*)&Ws[k][tn];
      acc[0][0] += a4.x*w4.x; acc[0][1] += a4.x*w4.y; acc[0][2] += a4.x*w4.z; acc[0][3] += a4.x*w4.w;
      acc[1][0] += a4.y*w4.x; acc[1][1] += a4.y*w4.y; acc[1][2] += a4.y*w4.z; acc[1][3] += a4.y*w4.w;
      acc[2][0] += a4.z*w4.x; acc[2][1] += a4.z*w4.y; acc[2][2] += a4.z*w4.z; acc[2][3] += a4.z*w4.w;
      acc[3][0] += a4.w*w4.x; acc[3][1] += a4.w*w4.y; acc[3][2] += a4.w*w4.z; acc[3][3] += a4.w*w4.w;
    }
    __syncthreads();
  }
  float* p = part + (long)s*BB*2048;
  #pragma unroll
  for (int i = 0; i < 4; i++)
    #pragma unroll
    for (int j = 0; j < 4; j++)
      p[(long)(tb + i)*2048 + n0 + tn + j] = acc[i][j];
}

// ---------------- main LSTM: reduce 4 partials + biases + elementwise ----------------
__global__ void k_lstm_l(const float* __restrict__ part, const float* __restrict__ bih,
                         const float* __restrict__ bhh, const float* __restrict__ c0,
                         float* __restrict__ h1, float* __restrict__ c1){
  int idx = blockIdx.x*256 + threadIdx.x;    // 64*512
  if (idx >= BB*HH) return;
  int b = idx >> 9, j = idx & 511;
  float gv[4];
  #pragma unroll
  for (int gi = 0; gi < 4; gi++){
    int n = gi*512 + j;
    float s = bih[n] + bhh[n];
    #pragma unroll
    for (int sp = 0; sp < 4; sp++) s += part[(long)sp*BB*2048 + (long)b*2048 + n];
    gv[gi] = s;
  }
  float c2 = sigmoidf(gv[1])*c0[idx] + sigmoidf(gv[0])*tanhf(gv[2]);
  h1[idx] = sigmoidf(gv[3])*tanhf(c2);
  c1[idx] = c2;
}

// ---------------- logits GEMM: C(64,50000) = c1(64,512) @ out_W^T + out_b ----------------
__global__ __launch_bounds__(256) void k_gemm_logits(const float* __restrict__ A,
                                                     const float* __restrict__ W,
                                                     const float* __restrict__ bias,
                                                     float* __restrict__ C){
  __shared__ __align__(16) float As[32][68];
  __shared__ __align__(16) float Ws[32][68];
  int tid = threadIdx.x;
  int n0  = blockIdx.x * 64;
  int tn  = (tid & 15) * 4;
  int tb  = (tid >> 4) * 4;
  int kk  = tid & 31;
  int r0  = tid >> 5;
  float acc[4][4] = {};
  for (int k0 = 0; k0 < HH; k0 += 32){
    int kg = k0 + kk;
    #pragma unroll
    for (int i = 0; i < 8; i++){
      int b = r0 + i*8;
      As[kk][b] = A[(long)b*HH + kg];
      int n = n0 + r0 + i*8;
      Ws[kk][r0 + i*8] = (n < VV) ? W[(long)n*HH + kg] : 0.0f;
    }
    __syncthreads();
    #pragma unroll
    for (int k = 0; k < 32; k++){
      float4 a4 = *(const float4*)&As[k][tb];
      float4 w4 = *(const float4*)&Ws[k][tn];
      acc[0][0] += a4.x*w4.x; acc[0][1] += a4.x*w4.y; acc[0][2] += a4.x*w4.z; acc[0][3] += a4.x*w4.w;
      acc[1][0] += a4.y*w4.x; acc[1][1] += a4.y*w4.y; acc[1][2] += a4.y*w4.z; acc[1][3] += a4.y*w4.w;
      acc[2][0] += a4.z*w4.x; acc[2][1] += a4.z*w4.y; acc[2][2] += a4.z*w4.z; acc[2][3] += a4.z*w4.w;
      acc[3][0] += a4.w*w4.x; acc[3][1] += a4.w*w4.y; acc[3][2] += a4.w*w4.z; acc[3][3] += a4.w*w4.w;
    }
    __syncthreads();
  }
  #pragma unroll
  for (int i = 0; i < 4; i++){
    #pragma unroll
    for (int j = 0; j < 4; j++){
      int n = n0 + tn + j;
      if (n < VV) C[(long)(tb + i)*VV + n] = acc[i][j] + bias[n];
    }
  }
}

// ---------------- 3-stage log_softmax over V ----------------
__global__ __launch_bounds__(256) void k_ls1(const float* __restrict__ lp,
                                             float* __restrict__ pm, float* __restrict__ ps){
  int b = blockIdx.y, c = blockIdx.x, t = threadIdx.x;   // grid (25, 64)
  const float* row = lp + (long)b*VV + c*2000;
  float mx = -INFINITY;
  for (int i = t; i < 2000; i += 256) mx = fmaxf(mx, row[i]);
  __shared__ float sm[4], ss[4];
  mx = wave_max(mx);
  if ((t & 63) == 0) sm[t>>6] = mx;
  __syncthreads();
  mx = fmaxf(fmaxf(sm[0], sm[1]), fmaxf(sm[2], sm[3]));
  float s = 0.f;
  for (int i = t; i < 2000; i += 256) s += expf(row[i] - mx);
  s = wave_sum(s);
  if ((t & 63) == 0) ss[t>>6] = s;
  __syncthreads();
  if (t == 0){ pm[b*25 + c] = mx; ps[b*25 + c] = ss[0]+ss[1]+ss[2]+ss[3]; }
}

__global__ void k_ls2(const float* __restrict__ pm, const float* __restrict__ ps,
                      float* __restrict__ lse){
  int b = threadIdx.x;    // 64
  float m = -INFINITY;
  for (int c = 0; c < 25; c++) m = fmaxf(m, pm[b*25 + c]);
  float s = 0.f;
  for (int c = 0; c < 25; c++) s += ps[b*25 + c]*expf(pm[b*25 + c] - m);
  lse[b] = m + logf(s);
}

__global__ void k_ls3(float* __restrict__ lp, const float* __restrict__ lse){
  int idx = blockIdx.x*256 + threadIdx.x;
  if (idx >= BB*VV) return;
  int b = idx / VV;
  lp[idx] -= lse[b];
}

extern "C" void kernel_launch(void* const* d_in, const int* in_sizes, int n_in,
                              void* d_out, int out_size, void* d_ws, size_t ws_size,
                              hipStream_t stream) {
  const int*   ids     = (const int*)  d_in[0];
  const float* h0      = (const float*)d_in[1];
  const float* c0      = (const float*)d_in[2];
  const float* enc     = (const float*)d_in[3];
  const float* cov     = (const float*)d_in[5];
  const float* mem     = (const float*)d_in[6];
  const float* rheads  = (const float*)d_in[7];
  const float* wheads  = (const float*)d_in[8];
  const float* read_h  = (const float*)d_in[9];
  const float* read_c  = (const float*)d_in[10];
  const float* write_h = (const float*)d_in[11];
  const float* write_c = (const float*)d_in[12];
  const float* emb     = (const float*)d_in[13];
  const float* attn_W  = (const float*)d_in[14];
  const float* attn_b  = (const float*)d_in[15];
  const float* cov_W   = (const float*)d_in[16];
  const float* state_W = (const float*)d_in[17];
  const float* comb_W  = (const float*)d_in[18];
  const float* comb_b  = (const float*)d_in[19];
  const float* rpre_W  = (const float*)d_in[20];
  const float* rpre_b  = (const float*)d_in[21];
  const float* wpre_W  = (const float*)d_in[22];
  const float* wpre_b  = (const float*)d_in[23];
  const float* r_Wih   = (const float*)d_in[24];
  const float* r_Whh   = (const float*)d_in[25];
  const float* r_bih   = (const float*)d_in[26];
  const float* r_bhh   = (const float*)d_in[27];
  const float* w_Wih   = (const float*)d_in[28];
  const float* w_Whh   = (const float*)d_in[29];
  const float* w_bih   = (const float*)d_in[30];
  const float* w_bhh   = (const float*)d_in[31];
  const float* l_Wih   = (const float*)d_in[32];
  const float* l_Whh   = (const float*)d_in[33];
  const float* l_bih   = (const float*)d_in[34];
  const float* l_bhh   = (const float*)d_in[35];
  const float* out_W   = (const float*)d_in[36];
  const float* out_b   = (const float*)d_in[37];

  float* out  = (float*)d_out;
  float* lp   = out;                 // (64, 50000)
  float* h1   = out + 3200000;       // (64, 512)
  float* c1   = h1 + 32768;          // (64, 512)
  float* nmem = c1 + 32768;          // (64, 128, 64)
  float* ncov = nmem + 524288;       // (64, 400)

  float* w = (float*)d_ws;
  float* xcat1 = w;                  // 65536   [embedded | h0]
  float* xcat2 = xcat1 + 65536;      // 65536   [embedded | attn_applied]
  float* xcat3 = xcat2 + 65536;      // 36864   [out0 | read_in]
  float* ia    = xcat3 + 36864;      // 25600
  float* ts    = ia + 25600;         // 25600
  float* tc    = ts + 25600;         // 25600
  float* aw    = tc + 25600;         // 25600
  float* U     = aw + 25600;         // 557056  shared: apart(524288)/ppart(557056)/lpart(524288)
  float* pre_r = U + 557056;         // 4096
  float* pre_w = pre_r + 4096;       // 4096
  float* g_r   = pre_w + 4096;       // 66560
  float* g_w   = g_r + 66560;        // 66560
  float* rh    = g_w + 66560;        // 16640
  float* wh    = rh + 16640;         // 16640
  float* rw    = wh + 16640;         // 8192
  float* wwgt  = rw + 8192;          // 8192
  float* pm    = wwgt + 8192;        // 1600
  float* ps    = pm + 1600;          // 1600
  float* lse   = ps + 1600;          // 64

  // attention path
  k_embed<<<128, 256, 0, stream>>>(ids, emb, h0, xcat1, xcat2);
  k_gemv<1,0><<<dim3(100,64), 256, 0, stream>>>(xcat1, xcat1, attn_W, attn_b, ia, 1024, LL, LL);
  k_gemv<0,0><<<dim3(100,64), 256, 0, stream>>>(c0, c0, state_W, nullptr, ts, HH, LL, LL);
  k_cov<<<100, 256, 0, stream>>>(cov, ia, ncov);
  k_gemv<0,1><<<dim3(100,64), 256, 0, stream>>>(cov, ia, cov_W, nullptr, tc, LL, LL, LL);
  k_softmax_aw<<<64, 256, 0, stream>>>(ia, ts, tc, aw);
  k_attn_part<<<dim3(64,16), 256, 0, stream>>>(aw, enc, U);
  k_attn_reduce<<<128, 256, 0, stream>>>(U, xcat2);
  k_gemv<1,0><<<dim3(128,64), 256, 0, stream>>>(xcat2, xcat2, comb_W, comb_b, xcat3, 1024, HH, 576);

  // pre-projections (K=8704, 68-way split)
  k_pre_partial<<<dim3(68,2), 256, 0, stream>>>(h0, mem, rpre_W, wpre_W, U);
  k_pre_reduce<<<32, 256, 0, stream>>>(U, rpre_b, wpre_b, pre_r, pre_w);

  // read/write head gates + LSTMs (fused)
  k_gates_rw<<<dim3(260,64,2), 256, 0, stream>>>(pre_r, pre_w, read_h, write_h,
      r_Wih, r_Whh, r_bih, r_bhh, w_Wih, w_Whh, w_bih, w_bhh, g_r, g_w);
  k_lstm_rw<<<130, 256, 0, stream>>>(g_r, g_w, read_c, write_c, rh, wh);

  // addressing + memory ops
  k_address<<<dim3(64,2), 128, 0, stream>>>(rh, wh, rheads, wheads, mem, rw, wwgt);
  k_readin<<<64, 64, 0, stream>>>(rw, mem, xcat3);
  k_newmem<<<2048, 256, 0, stream>>>(mem, wwgt, wh, nmem);

  // main LSTM (K-split partials + fused reduce/elementwise)
  k_lgates_part<<<dim3(32,4), 256, 0, stream>>>(xcat3, h0, l_Wih, l_Whh, U);
  k_lstm_l<<<128, 256, 0, stream>>>(U, l_bih, l_bhh, c0, h1, c1);

  // output projection + log_softmax
  k_gemm_logits<<<782, 256, 0, stream>>>(c1, out_W, out_b, lp);
  k_ls1<<<dim3(25,64), 256, 0, stream>>>(lp, pm, ps);
  k_ls2<<<1, 64, 0, stream>>>(pm, ps, lse);
  k_ls3<<<12500, 256, 0, stream>>>(lp, lse);
}

// Round 3
// 503.663 us; speedup vs baseline: 3.2851x; 1.1117x over previous
//
#include <hip/hip_runtime.h>
#include <math.h>

#define BB 64
#define HH 512
#define VV 50000
#define LL 400
#define MM 128
#define DD 64
#define HC 260
#define EPSF 1e-8f

typedef __attribute__((ext_vector_type(8))) short bf16x8;
typedef __attribute__((ext_vector_type(4))) float f32x4;

__device__ __forceinline__ float sigmoidf(float x){ return 1.0f/(1.0f+expf(-x)); }
__device__ __forceinline__ unsigned short bf16_rne(float f){
  unsigned u = __float_as_uint(f);
  return (unsigned short)((u + 0x7fffu + ((u >> 16) & 1u)) >> 16);
}
__device__ __forceinline__ float wave_max(float v){
  #pragma unroll
  for(int o=32;o;o>>=1) v = fmaxf(v, __shfl_xor(v,o));
  return v;
}
__device__ __forceinline__ float wave_sum(float v){
  #pragma unroll
  for(int o=32;o;o>>=1) v += __shfl_xor(v,o);
  return v;
}

// ---------------- embed + concat builders ----------------
__global__ void k_embed(const int* __restrict__ ids, const float* __restrict__ emb,
                        const float* __restrict__ h0, float* __restrict__ xcat1,
                        float* __restrict__ xcat2){
  int idx = blockIdx.x*256 + threadIdx.x;           // 64*512
  if (idx >= BB*HH) return;
  int b = idx >> 9, h = idx & 511;
  float e = emb[(long)ids[b]*HH + h];
  xcat1[b*1024 + h] = e;
  xcat2[b*1024 + h] = e;
  xcat1[b*1024 + 512 + h] = h0[idx];
}

// ---------------- wave-per-output GEMV: C[b,n] = (A[+A2])[b,:] . W[n,:] ----------------
template<int NB, int FUSE>
__global__ __launch_bounds__(256) void k_gemv(const float* __restrict__ A,
                                              const float* __restrict__ A2,
                                              const float* __restrict__ W,
                                              const float* __restrict__ b1,
                                              float* __restrict__ C,
                                              int K, int N, int ldc){
  int b = blockIdx.y;
  int wid = threadIdx.x >> 6, lane = threadIdx.x & 63;
  int n = blockIdx.x*4 + wid;
  if (n >= N) return;
  const float4* A4  = (const float4*)(A + (long)b*K);
  const float4* A24 = (const float4*)(A2 + (long)b*K);
  const float4* W4  = (const float4*)(W + (long)n*K);
  int K4 = K >> 2;
  float acc = 0.f;
  for (int k = lane; k < K4; k += 64){
    float4 a = A4[k];
    if (FUSE){ float4 a2 = A24[k]; a.x+=a2.x; a.y+=a2.y; a.z+=a2.z; a.w+=a2.w; }
    float4 w = W4[k];
    acc += a.x*w.x + a.y*w.y + a.z*w.z + a.w*w.w;
  }
  acc = wave_sum(acc);
  if (lane == 0){
    if (NB) acc += b1[n];
    C[(long)b*ldc + n] = acc;
  }
}

// ---------------- new_coverage = coverage + ia ----------------
__global__ void k_cov(const float* __restrict__ cov, const float* __restrict__ ia,
                      float* __restrict__ out){
  int idx = blockIdx.x*256 + threadIdx.x;     // 25600
  if (idx >= BB*LL) return;
  out[idx] = cov[idx] + ia[idx];
}

// ---------------- aw = softmax(tc+ia+ts) over L ----------------
__global__ __launch_bounds__(256) void k_softmax_aw(const float* __restrict__ ia,
                                                    const float* __restrict__ ts,
                                                    const float* __restrict__ tc,
                                                    float* __restrict__ aw){
  int b = blockIdx.x, t = threadIdx.x;
  int i0 = t, i1 = t + 256;
  float x0 = ia[b*LL+i0] + ts[b*LL+i0] + tc[b*LL+i0];
  float x1 = (i1 < LL) ? (ia[b*LL+i1] + ts[b*LL+i1] + tc[b*LL+i1]) : -INFINITY;
  __shared__ float sm[4], ss[4];
  float m = wave_max(fmaxf(x0, x1));
  if ((t & 63) == 0) sm[t>>6] = m;
  __syncthreads();
  m = fmaxf(fmaxf(sm[0], sm[1]), fmaxf(sm[2], sm[3]));
  float e0 = expf(x0 - m);
  float e1 = (i1 < LL) ? expf(x1 - m) : 0.0f;
  float s = wave_sum(e0 + e1);
  if ((t & 63) == 0) ss[t>>6] = s;
  __syncthreads();
  float tot = ss[0] + ss[1] + ss[2] + ss[3];
  float inv = 1.0f / tot;
  aw[b*LL + i0] = e0 * inv;
  if (i1 < LL) aw[b*LL + i1] = e1 * inv;
}

// ---------------- attn_applied partials: grid (64 b, 16 l-chunks of 25) ----------------
__global__ __launch_bounds__(256) void k_attn_part(const float* __restrict__ aw,
                                                   const float* __restrict__ enc,
                                                   float* __restrict__ part){
  int b = blockIdx.x, lc = blockIdx.y, t = threadIdx.x;
  const float* awb = aw + b*LL + lc*25;
  const float* eb  = enc + ((long)b*LL + lc*25)*HH;
  float a0 = 0.f, a1 = 0.f;
  for (int l = 0; l < 25; l++){
    float a = awb[l];
    a0 += a * eb[(long)l*HH + t];
    a1 += a * eb[(long)l*HH + t + 256];
  }
  part[((b*16 + lc) << 9) + t]       = a0;
  part[((b*16 + lc) << 9) + t + 256] = a1;
}

__global__ void k_attn_reduce(const float* __restrict__ part, float* __restrict__ xcat2){
  int idx = blockIdx.x*256 + threadIdx.x;       // 64*512
  if (idx >= BB*HH) return;
  int b = idx >> 9, h = idx & 511;
  float s = 0.f;
  #pragma unroll
  for (int lc = 0; lc < 16; lc++) s += part[((b*16 + lc) << 9) + h];
  xcat2[b*1024 + 512 + h] = s;
}

// ---------------- pre GEMV, K-split: grid (16 n-quads, 64 b, which*8+chunk) ----------------
// pre = [h0 | mem] @ {r,w}pre_W^T ; K=8704 split into 8 chunks of 1088.
__global__ __launch_bounds__(256) void k_pre_gemv(const float* __restrict__ h0,
                                                  const float* __restrict__ mem,
                                                  const float* __restrict__ rW,
                                                  const float* __restrict__ wW,
                                                  float* __restrict__ part){
  int wid = threadIdx.x >> 6, lane = threadIdx.x & 63;
  int n = blockIdx.x*4 + wid;        // 0..63
  int b = blockIdx.y;
  int z = blockIdx.z;                // which*8 + chunk
  int which = z >> 3, chunk = z & 7;
  const float* W = which ? wW : rW;
  const float4* W4 = (const float4*)(W + (long)n*8704 + chunk*1088);
  const float4* H4 = (const float4*)(h0 + (long)b*HH);
  const float4* M4 = (const float4*)(mem + (long)b*8192 + (chunk*1088 - 512));
  float acc = 0.f;
  #pragma unroll
  for (int i = 0; i < 5; i++){
    int k4 = lane + i*64;            // float4 index within chunk (272 total)
    if (k4 < 272){
      int kg4 = chunk*272 + k4;      // global float4 index
      float4 a = (kg4 < 128) ? H4[kg4] : M4[k4];
      float4 w = W4[k4];
      acc += a.x*w.x + a.y*w.y + a.z*w.z + a.w*w.w;
    }
  }
  acc = wave_sum(acc);
  if (lane == 0) part[z*4096 + b*64 + n] = acc;
}

__global__ void k_pre_reduce(const float* __restrict__ part, const float* __restrict__ rb,
                             const float* __restrict__ wb, float* __restrict__ pre_r,
                             float* __restrict__ pre_w){
  int idx = blockIdx.x*256 + threadIdx.x;     // 8192
  if (idx >= 8192) return;
  int which = idx >> 12;
  int r = idx & 4095;
  float s = 0.f;
  #pragma unroll
  for (int c = 0; c < 8; c++) s += part[((which<<3)+c)*4096 + r];
  int n = r & 63;
  s += which ? wb[n] : rb[n];
  (which ? pre_w : pre_r)[r] = s;
}

// ---------------- fused gates GEMV for r/w heads: grid (260, 64, 2) ----------------
__global__ __launch_bounds__(256) void k_gates_rw(const float* __restrict__ pre_r,
    const float* __restrict__ pre_w, const float* __restrict__ read_h,
    const float* __restrict__ write_h,
    const float* __restrict__ rWih, const float* __restrict__ rWhh,
    const float* __restrict__ rbih, const float* __restrict__ rbhh,
    const float* __restrict__ wWih, const float* __restrict__ wWhh,
    const float* __restrict__ wbih, const float* __restrict__ wbhh,
    float* __restrict__ g_r, float* __restrict__ g_w){
  int which = blockIdx.z;
  int b = blockIdx.y;
  int wid = threadIdx.x >> 6, lane = threadIdx.x & 63;
  int n = blockIdx.x*4 + wid;     // < 1040
  const float* pre = which ? pre_w : pre_r;     // (64,64)
  const float* hh  = which ? write_h : read_h;  // (64,260)
  const float* Wih = which ? wWih : rWih;       // (1040,64)
  const float* Whh = which ? wWhh : rWhh;       // (1040,260)
  float acc = pre[b*64 + lane] * Wih[n*64 + lane];
  const float* hb = hh + b*HC;
  const float* wr = Whh + (long)n*HC;
  #pragma unroll
  for (int i = 0; i < 5; i++){
    int k = lane + i*64;
    if (k < HC) acc += hb[k]*wr[k];
  }
  acc = wave_sum(acc);
  if (lane == 0){
    acc += (which ? wbih : rbih)[n] + (which ? wbhh : rbhh)[n];
    (which ? g_w : g_r)[(long)b*4*HC + n] = acc;
  }
}

// ---------------- fused r+w LSTM elementwise ----------------
__global__ void k_lstm_rw(const float* __restrict__ g_r, const float* __restrict__ g_w,
                          const float* __restrict__ read_c, const float* __restrict__ write_c,
                          float* __restrict__ rh, float* __restrict__ wh){
  int idx = blockIdx.x*256 + threadIdx.x;    // 2*64*260 = 33280
  if (idx >= 2*BB*HC) return;
  int which = idx >= BB*HC;
  int r = which ? idx - BB*HC : idx;
  int b = r / HC, j = r - b*HC;
  const float* g = (which ? g_w : g_r) + (long)b*4*HC;
  float c2 = sigmoidf(g[HC + j]) * (which ? write_c : read_c)[r]
           + sigmoidf(g[j]) * tanhf(g[2*HC + j]);
  (which ? wh : rh)[r] = sigmoidf(g[3*HC + j]) * tanhf(c2);
}

// ---------------- addressing: grid (64, 2), 128 threads ----------------
__global__ __launch_bounds__(128) void k_address(const float* __restrict__ rh,
                                                 const float* __restrict__ whv,
                                                 const float* __restrict__ rheads,
                                                 const float* __restrict__ wheads,
                                                 const float* __restrict__ mem,
                                                 float* __restrict__ rwout,
                                                 float* __restrict__ wwout){
  int which = blockIdx.y;
  int b = blockIdx.x, m = threadIdx.x;
  const float* hc = which ? whv : rh;
  const float* heads0 = which ? wheads : rheads;
  float* wout = which ? wwout : rwout;
  const float* mr = mem + ((long)b*MM + m)*DD;
  float s = 0.f, q = 0.f;
  #pragma unroll 8
  for (int d = 0; d < DD; d++){ float v = mr[d]; s += v; q += v*v; }
  float key  = hc[b*HC + m];
  float kstr = expf(hc[b*HC + 64]);
  float gate = sigmoidf(hc[b*HC + 65]);
  float nk = fmaxf(fabsf(key)*8.0f, EPSF);
  float nm = fmaxf(sqrtf(q), EPSF);
  float z  = kstr * (key*s) / (nk*nm);
  __shared__ float sm[2], ss[2];
  float mx = wave_max(z);
  if ((m & 63) == 0) sm[m>>6] = mx;
  __syncthreads();
  mx = fmaxf(sm[0], sm[1]);
  float e = expf(z - mx);
  float w = wave_sum(e);
  if ((m & 63) == 0) ss[m>>6] = w;
  __syncthreads();
  float content = e / (ss[0] + ss[1]);
  wout[b*MM + m] = gate*content + (1.0f - gate)*heads0[m];   // heads[0]: batch-0 row broadcast
}

// ---------------- read_in -> xcat3[:,512:576] ----------------
__global__ void k_readin(const float* __restrict__ rw, const float* __restrict__ mem,
                         float* __restrict__ xcat3){
  int b = blockIdx.x, d = threadIdx.x;    // 64 threads
  float s = 0.f;
  for (int m = 0; m < MM; m++) s += rw[b*MM + m] * mem[((long)b*MM + m)*DD + d];
  xcat3[b*576 + 512 + d] = s;
}

// ---------------- new_memory ----------------
__global__ void k_newmem(const float* __restrict__ mem, const float* __restrict__ ww,
                         const float* __restrict__ wh, float* __restrict__ out){
  int idx = blockIdx.x*256 + threadIdx.x;    // 524288
  if (idx >= BB*MM*DD) return;
  int b = idx >> 13;
  int m = (idx & 8191) >> 6;
  float w0 = ww[b*MM + m];
  float we = sigmoidf(wh[b*HC + 68 + m]);
  float wa = sigmoidf(wh[b*HC + 132 + m]);
  out[idx] = mem[idx]*(1.0f - w0*we) + w0*wa;
}

// ---------------- main LSTM fused: wave per (b,j) computes 4 gate dots + elementwise ----
// grid (128 j-quads, 64 b), 256 threads (4 waves). Also emits c1 as bf16 (c1b).
__global__ __launch_bounds__(256) void k_lstm_main(const float* __restrict__ xcat3,
                                                   const float* __restrict__ h0,
                                                   const float* __restrict__ lWih,
                                                   const float* __restrict__ lWhh,
                                                   const float* __restrict__ bih,
                                                   const float* __restrict__ bhh,
                                                   const float* __restrict__ c0,
                                                   float* __restrict__ h1,
                                                   float* __restrict__ c1,
                                                   unsigned short* __restrict__ c1b){
  int wid = threadIdx.x >> 6, lane = threadIdx.x & 63;
  int j = blockIdx.x*4 + wid;        // 0..511
  int b = blockIdx.y;
  const float4* A1 = (const float4*)(xcat3 + (long)b*576);   // 144 f4
  const float4* A2 = (const float4*)(h0 + (long)b*HH);       // 128 f4
  float gv[4];
  #pragma unroll
  for (int g = 0; g < 4; g++){
    int n = g*HH + j;
    const float4* W1 = (const float4*)(lWih + (long)n*576);
    const float4* W2 = (const float4*)(lWhh + (long)n*HH);
    float s = 0.f;
    #pragma unroll
    for (int i = 0; i < 3; i++){
      int k = lane + i*64;
      if (k < 144){ float4 a = A1[k], w = W1[k]; s += a.x*w.x + a.y*w.y + a.z*w.z + a.w*w.w; }
    }
    #pragma unroll
    for (int i = 0; i < 2; i++){
      int k = lane + i*64;
      float4 a = A2[k], w = W2[k]; s += a.x*w.x + a.y*w.y + a.z*w.z + a.w*w.w;
    }
    gv[g] = wave_sum(s);
  }
  if (lane == 0){
    #pragma unroll
    for (int g = 0; g < 4; g++){ int n = g*HH + j; gv[g] += bih[n] + bhh[n]; }
    float c2 = sigmoidf(gv[1])*c0[b*HH + j] + sigmoidf(gv[0])*tanhf(gv[2]);
    h1[b*HH + j] = sigmoidf(gv[3])*tanhf(c2);
    c1[b*HH + j] = c2;
    c1b[b*HH + j] = bf16_rne(c2);
  }
}

// ---------------- logits: bf16 MFMA, no LDS. wave per 16-wide n-strip x all 64 m. ------
// C(64,50000) = c1b(64,512,bf16) @ out_W^T(fp32->bf16 on the fly) + bias
__global__ __launch_bounds__(256) void k_logits_mfma(const unsigned short* __restrict__ Ab,
                                                     const float* __restrict__ W,
                                                     const float* __restrict__ bias,
                                                     float* __restrict__ C){
  int wid = threadIdx.x >> 6, lane = threadIdx.x & 63;
  int strip = blockIdx.x*4 + wid;          // 3125 strips of 16 n
  if (strip >= 3125) return;
  int nl = lane & 15;                      // n offset within strip / m offset in frags
  int q  = lane >> 4;                      // quad -> k = q*8 + j
  int n  = strip*16 + nl;
  const float* wrow = W + (long)n*HH + q*8;
  const unsigned short* a0p = Ab + (0*16 + nl)*HH + q*8;
  const unsigned short* a1p = Ab + (1*16 + nl)*HH + q*8;
  const unsigned short* a2p = Ab + (2*16 + nl)*HH + q*8;
  const unsigned short* a3p = Ab + (3*16 + nl)*HH + q*8;
  f32x4 acc0 = {0.f,0.f,0.f,0.f}, acc1 = acc0, acc2 = acc0, acc3 = acc0;
  #pragma unroll 4
  for (int ks = 0; ks < 16; ks++){
    const float4* wp = (const float4*)(wrow + ks*32);
    float4 w0 = wp[0];
    float4 w1 = wp[1];
    bf16x8 bf;
    bf[0] = (short)bf16_rne(w0.x); bf[1] = (short)bf16_rne(w0.y);
    bf[2] = (short)bf16_rne(w0.z); bf[3] = (short)bf16_rne(w0.w);
    bf[4] = (short)bf16_rne(w1.x); bf[5] = (short)bf16_rne(w1.y);
    bf[6] = (short)bf16_rne(w1.z); bf[7] = (short)bf16_rne(w1.w);
    bf16x8 a0 = *(const bf16x8*)(a0p + ks*32);
    bf16x8 a1 = *(const bf16x8*)(a1p + ks*32);
    bf16x8 a2 = *(const bf16x8*)(a2p + ks*32);
    bf16x8 a3 = *(const bf16x8*)(a3p + ks*32);
    acc0 = __builtin_amdgcn_mfma_f32_16x16x32_bf16(a0, bf, acc0, 0, 0, 0);
    acc1 = __builtin_amdgcn_mfma_f32_16x16x32_bf16(a1, bf, acc1, 0, 0, 0);
    acc2 = __builtin_amdgcn_mfma_f32_16x16x32_bf16(a2, bf, acc2, 0, 0, 0);
    acc3 = __builtin_amdgcn_mfma_f32_16x16x32_bf16(a3, bf, acc3, 0, 0, 0);
  }
  float bv = bias[n];
  #pragma unroll
  for (int r = 0; r < 4; r++){
    int m = q*4 + r;
    C[(long)(m     )*VV + n] = acc0[r] + bv;
    C[(long)(m + 16)*VV + n] = acc1[r] + bv;
    C[(long)(m + 32)*VV + n] = acc2[r] + bv;
    C[(long)(m + 48)*VV + n] = acc3[r] + bv;
  }
}

// ---------------- 3-stage log_softmax over V ----------------
__global__ __launch_bounds__(256) void k_ls1(const float* __restrict__ lp,
                                             float* __restrict__ pm, float* __restrict__ ps){
  int b = blockIdx.y, c = blockIdx.x, t = threadIdx.x;   // grid (25, 64)
  const float* row = lp + (long)b*VV + c*2000;
  float mx = -INFINITY;
  for (int i = t; i < 2000; i += 256) mx = fmaxf(mx, row[i]);
  __shared__ float sm[4], ss[4];
  mx = wave_max(mx);
  if ((t & 63) == 0) sm[t>>6] = mx;
  __syncthreads();
  mx = fmaxf(fmaxf(sm[0], sm[1]), fmaxf(sm[2], sm[3]));
  float s = 0.f;
  for (int i = t; i < 2000; i += 256) s += expf(row[i] - mx);
  s = wave_sum(s);
  if ((t & 63) == 0) ss[t>>6] = s;
  __syncthreads();
  if (t == 0){ pm[b*25 + c] = mx; ps[b*25 + c] = ss[0]+ss[1]+ss[2]+ss[3]; }
}

__global__ void k_ls2(const float* __restrict__ pm, const float* __restrict__ ps,
                      float* __restrict__ lse){
  int b = threadIdx.x;    // 64
  float m = -INFINITY;
  for (int c = 0; c < 25; c++) m = fmaxf(m, pm[b*25 + c]);
  float s = 0.f;
  for (int c = 0; c < 25; c++) s += ps[b*25 + c]*expf(pm[b*25 + c] - m);
  lse[b] = m + logf(s);
}

__global__ void k_ls3(float* __restrict__ lp, const float* __restrict__ lse){
  int idx = blockIdx.x*256 + threadIdx.x;
  if (idx >= BB*VV) return;
  int b = idx / VV;
  lp[idx] -= lse[b];
}

extern "C" void kernel_launch(void* const* d_in, const int* in_sizes, int n_in,
                              void* d_out, int out_size, void* d_ws, size_t ws_size,
                              hipStream_t stream) {
  const int*   ids     = (const int*)  d_in[0];
  const float* h0      = (const float*)d_in[1];
  const float* c0      = (const float*)d_in[2];
  const float* enc     = (const float*)d_in[3];
  const float* cov     = (const float*)d_in[5];
  const float* mem     = (const float*)d_in[6];
  const float* rheads  = (const float*)d_in[7];
  const float* wheads  = (const float*)d_in[8];
  const float* read_h  = (const float*)d_in[9];
  const float* read_c  = (const float*)d_in[10];
  const float* write_h = (const float*)d_in[11];
  const float* write_c = (const float*)d_in[12];
  const float* emb     = (const float*)d_in[13];
  const float* attn_W  = (const float*)d_in[14];
  const float* attn_b  = (const float*)d_in[15];
  const float* cov_W   = (const float*)d_in[16];
  const float* state_W = (const float*)d_in[17];
  const float* comb_W  = (const float*)d_in[18];
  const float* comb_b  = (const float*)d_in[19];
  const float* rpre_W  = (const float*)d_in[20];
  const float* rpre_b  = (const float*)d_in[21];
  const float* wpre_W  = (const float*)d_in[22];
  const float* wpre_b  = (const float*)d_in[23];
  const float* r_Wih   = (const float*)d_in[24];
  const float* r_Whh   = (const float*)d_in[25];
  const float* r_bih   = (const float*)d_in[26];
  const float* r_bhh   = (const float*)d_in[27];
  const float* w_Wih   = (const float*)d_in[28];
  const float* w_Whh   = (const float*)d_in[29];
  const float* w_bih   = (const float*)d_in[30];
  const float* w_bhh   = (const float*)d_in[31];
  const float* l_Wih   = (const float*)d_in[32];
  const float* l_Whh   = (const float*)d_in[33];
  const float* l_bih   = (const float*)d_in[34];
  const float* l_bhh   = (const float*)d_in[35];
  const float* out_W   = (const float*)d_in[36];
  const float* out_b   = (const float*)d_in[37];

  float* out  = (float*)d_out;
  float* lp   = out;                 // (64, 50000)
  float* h1   = out + 3200000;       // (64, 512)
  float* c1   = h1 + 32768;          // (64, 512)
  float* nmem = c1 + 32768;          // (64, 128, 64)
  float* ncov = nmem + 524288;       // (64, 400)

  float* w = (float*)d_ws;
  float* xcat1 = w;                  // 65536   [embedded | h0]
  float* xcat2 = xcat1 + 65536;      // 65536   [embedded | attn_applied]
  float* xcat3 = xcat2 + 65536;      // 36864   [out0 | read_in]
  float* ia    = xcat3 + 36864;      // 25600
  float* ts    = ia + 25600;         // 25600
  float* tc    = ts + 25600;         // 25600
  float* aw    = tc + 25600;         // 25600
  float* U     = aw + 25600;         // 557056  shared: attn partials(524288) / pre partials(65536)
  float* pre_r = U + 557056;         // 4096
  float* pre_w = pre_r + 4096;       // 4096
  float* g_r   = pre_w + 4096;       // 66560
  float* g_w   = g_r + 66560;        // 66560
  float* rh    = g_w + 66560;        // 16640
  float* wh    = rh + 16640;         // 16640
  float* rw    = wh + 16640;         // 8192
  float* wwgt  = rw + 8192;          // 8192
  float* pm    = wwgt + 8192;        // 1600
  float* ps    = pm + 1600;          // 1600
  float* lse   = ps + 1600;          // 64
  unsigned short* c1b = (unsigned short*)(lse + 64);   // 32768 bf16 (16384 floats)

  // attention path
  k_embed<<<128, 256, 0, stream>>>(ids, emb, h0, xcat1, xcat2);
  k_gemv<1,0><<<dim3(100,64), 256, 0, stream>>>(xcat1, xcat1, attn_W, attn_b, ia, 1024, LL, LL);
  k_gemv<0,0><<<dim3(100,64), 256, 0, stream>>>(c0, c0, state_W, nullptr, ts, HH, LL, LL);
  k_cov<<<100, 256, 0, stream>>>(cov, ia, ncov);
  k_gemv<0,1><<<dim3(100,64), 256, 0, stream>>>(cov, ia, cov_W, nullptr, tc, LL, LL, LL);
  k_softmax_aw<<<64, 256, 0, stream>>>(ia, ts, tc, aw);
  k_attn_part<<<dim3(64,16), 256, 0, stream>>>(aw, enc, U);
  k_attn_reduce<<<128, 256, 0, stream>>>(U, xcat2);
  k_gemv<1,0><<<dim3(128,64), 256, 0, stream>>>(xcat2, xcat2, comb_W, comb_b, xcat3, 1024, HH, 576);

  // pre-projections (K=8704, 8-way K-split GEMV)
  k_pre_gemv<<<dim3(16,64,16), 256, 0, stream>>>(h0, mem, rpre_W, wpre_W, U);
  k_pre_reduce<<<32, 256, 0, stream>>>(U, rpre_b, wpre_b, pre_r, pre_w);

  // read/write head gates + LSTMs (fused)
  k_gates_rw<<<dim3(260,64,2), 256, 0, stream>>>(pre_r, pre_w, read_h, write_h,
      r_Wih, r_Whh, r_bih, r_bhh, w_Wih, w_Whh, w_bih, w_bhh, g_r, g_w);
  k_lstm_rw<<<130, 256, 0, stream>>>(g_r, g_w, read_c, write_c, rh, wh);

  // addressing + memory ops
  k_address<<<dim3(64,2), 128, 0, stream>>>(rh, wh, rheads, wheads, mem, rw, wwgt);
  k_readin<<<64, 64, 0, stream>>>(rw, mem, xcat3);
  k_newmem<<<2048, 256, 0, stream>>>(mem, wwgt, wh, nmem);

  // main LSTM (fused gates GEMV + elementwise, emits bf16 c1)
  k_lstm_main<<<dim3(128,64), 256, 0, stream>>>(xcat3, h0, l_Wih, l_Whh, l_bih, l_bhh,
                                                c0, h1, c1, c1b);

  // output projection (bf16 MFMA) + log_softmax
  k_logits_mfma<<<782, 256, 0, stream>>>(c1b, out_W, out_b, lp);
  k_ls1<<<dim3(25,64), 256, 0, stream>>>(lp, pm, ps);
  k_ls2<<<1, 64, 0, stream>>>(pm, ps, lse);
  k_ls3<<<12500, 256, 0, stream>>>(lp, lse);
}